// Round 9
// baseline (236.526 us; speedup 1.0000x reference)
//
#include <hip/hip_runtime.h>
#include <hip/hip_bf16.h>

// DirectEncodingModel via MFMA (transposed: D^T = mfma(W-frag, act-frag)).
// Block = 1024 thr (16 waves) owns a 16-row acc tile in LDS; wave w does 4
// groups/layer; persistent grid=256, 4 tiles/block.
// R9 (LDS-pipe-bound fix; LDS audit showed ~19.6k cyc/CU-tile == kernel time):
//  - gather offsets live in PERSISTENT VGPRs (packed u16, staged via LDS once,
//    14 ds_read_b128 per lane at kernel start) -> zero per-tile offset reads.
//  - layer-1 gathers read raw fp32 x DIRECTLY from global (idx1<512 always),
//    VM pipe instead of LDS; same RNE f2bf -> numerics identical. Bias slot
//    (quad3) substituted with constants via cndmask.
//  - bias rides in K-pad slot k=24/k=48 against a 1.0 pad column (layers 2,3,
//    head); C starts at 0.
// Layouts (HW-verified): A[m=lane&15][k=(lane>>4)*8+j];
//   B[k=(lane>>4)*8+j][n=lane&15]; C/D col=lane&15, row=(lane>>4)*4+reg.

typedef unsigned short ushort_t;
typedef unsigned int uint_t;
typedef __attribute__((ext_vector_type(8))) short short8;   // 8 bf16 frag
typedef __attribute__((ext_vector_type(4))) float f32x4;    // MFMA acc

#define ACC_STRIDE 3588                   // u16 per row; 1794 dw == 2 mod 32
#define ROW_BYTES (ACC_STRIDE * 2)        // 7176
#define PAD_ONE 3584                      // pad col holding bf16 1.0
#define ONE_BYTE (PAD_ONE * 2)            // 7168
#define ZERO_BYTE (3586 * 2)              // 7172 (col 3586 == 0)
#define ACC_U16 (16 * ACC_STRIDE)         // 57408 u16 = 114816 B
#define TBL_BYTES 12800                   // compact offset table (u16)
#define LDS_BYTES (ACC_U16 * 2 + TBL_BYTES)    // 127616 B

// d_ws layout (bytes): frags hidden [0,196608) + head [196608,204800),
// then compact u16 offset table [204800, 217600).
#define OFF_B 204800

__device__ __forceinline__ ushort_t f2bf(float f) {
    __hip_bfloat16 h = __float2bfloat16(f);
    union { __hip_bfloat16 h; ushort_t u; } v;
    v.h = h;
    return v.u;
}

__device__ __forceinline__ uint_t pack2bf(float lo, float hi) {
    return (uint_t)f2bf(lo) | ((uint_t)f2bf(hi) << 16);
}

// tanh(x) = 1 - 2/(e^2x + 1); exp saturation gives exact +-1 tails, no clamp.
__device__ __forceinline__ float fast_tanh(float x) {
    float e = __expf(2.0f * x);
    return fmaf(-2.0f, __builtin_amdgcn_rcpf(e + 1.0f), 1.0f);
}

// ---- Pre-pack weights (B-frag order, bias in k=24/k=48 slot) + compact
// offset table: l=0 stores raw x element idx (global gather); l=1,2 store
// LDS byte offsets with K-pad -> ONE/ZERO pad cols; head likewise. ----
__global__ __launch_bounds__(256)
void convert_weights(const float* __restrict__ W1, const float* __restrict__ b1,
                     const float* __restrict__ W2, const float* __restrict__ b2,
                     const float* __restrict__ W3, const float* __restrict__ b3,
                     const float* __restrict__ Wo, const float* __restrict__ bo,
                     const int* __restrict__ idx1, const int* __restrict__ idx2,
                     const int* __restrict__ idx3, const int* __restrict__ idxo,
                     ushort_t* __restrict__ ws)
{
    const int tid = blockIdx.x * 256 + threadIdx.x;
    const int lane = tid & 63;
    const int nn = lane & 15;
    const int quad = lane >> 4;
    if (tid < 12288) {
        const int g = (tid >> 6) & 63;
        const int l = tid >> 12;   // 0..2
        const float* W = (l == 0) ? W1 : (l == 1) ? W2 : W3;
        const float* bb = (l == 0) ? b1 : (l == 1) ? b2 : b3;
        const float* Wg = W + g * 384;
        ushort_t v[8];
        #pragma unroll
        for (int j = 0; j < 8; ++j) {
            const int k = quad * 8 + j;
            v[j] = (k < 24) ? f2bf(Wg[k * 16 + nn])
                 : (k == 24) ? f2bf(bb[g * 16 + nn]) : (ushort_t)0;
        }
        ushort4* dst = reinterpret_cast<ushort4*>(ws + (size_t)tid * 8);
        dst[0] = make_ushort4(v[0], v[1], v[2], v[3]);
        dst[1] = make_ushort4(v[4], v[5], v[6], v[7]);
    } else if (tid < 12800) {
        const int h = tid - 12288;
        const int gs = h >> 6;          // 0..7: go*2+step
        const int go = gs >> 1;
        const int step = gs & 1;
        const float* Wg = Wo + go * 768;
        ushort_t v[8];
        #pragma unroll
        for (int j = 0; j < 8; ++j) {
            const int k = step * 32 + quad * 8 + j;
            v[j] = (k < 48) ? f2bf(Wg[k * 16 + nn])
                 : (k == 48) ? f2bf(bo[go * 16 + nn]) : (ushort_t)0;
        }
        ushort4* dst = reinterpret_cast<ushort4*>(ws + (size_t)tid * 8);
        dst[0] = make_ushort4(v[0], v[1], v[2], v[3]);
        dst[1] = make_ushort4(v[4], v[5], v[6], v[7]);
    } else if (tid < 18944) {
        // hidden compact offsets: e = l*2048 + g*32 + k  (u16)
        const int e = tid - 12800;
        const int l = e >> 11;
        const int g = (e >> 5) & 63;
        const int k = e & 31;
        ushort_t v;
        if (l == 0) {
            v = (k < 24) ? (ushort_t)idx1[g * 24 + k] : (ushort_t)0;  // elem idx
        } else {
            const int* idx = (l == 1) ? idx2 : idx3;
            v = (k < 24) ? (ushort_t)(idx[g * 24 + k] * 2)
              : (k == 24) ? (ushort_t)ONE_BYTE : (ushort_t)ZERO_BYTE;
        }
        reinterpret_cast<ushort_t*>((char*)ws + OFF_B)[e] = v;
    } else if (tid < 19200) {
        // head compact offsets: e = go*64 + k  (u16), appended after 6144
        const int e = tid - 18944;
        const int go = e >> 6;
        const int k = e & 63;
        const ushort_t v = (k < 48) ? (ushort_t)(idxo[go * 48 + k] * 2)
                         : (k == 48) ? (ushort_t)ONE_BYTE : (ushort_t)ZERO_BYTE;
        reinterpret_cast<ushort_t*>((char*)ws + OFF_B)[6144 + e] = v;
    }
}

#define NTILES 4   // 16384 rows / 16 per tile / 256 blocks

__global__ __launch_bounds__(1024)
void demodel_mfma(const float* __restrict__ x,
                  const ushort_t* __restrict__ ws,
                  float* __restrict__ out)
{
    extern __shared__ __align__(16) ushort_t smem[];
    const int t = threadIdx.x;
    const int lane = t & 63;
    const int wv = t >> 6;               // wave 0..15
    const int nn = lane & 15;
    const int quad = lane >> 4;
    const bool q3 = (quad == 3);

    // ---- stage compact offset table (12800 B) + pad cols ----
    if (t < TBL_BYTES / 16)
        reinterpret_cast<uint4*>(smem + ACC_U16)[t] =
            reinterpret_cast<const uint4*>((const char*)ws + OFF_B)[t];
    if (t < 16) {   // pad cols per row: [3584]=1.0, [3585..3587]=0
        uint2* p = reinterpret_cast<uint2*>((char*)smem + t * ROW_BYTES + ONE_BYTE);
        *p = make_uint2(0x00003f80u, 0u);
    }
    __syncthreads();

    // ---- hoist all gather offsets into persistent packed-u16 VGPRs ----
    const ushort_t* tbl = smem + ACC_U16;
    uint4 ofh[3][4];
    #pragma unroll
    for (int l = 0; l < 3; ++l)
        #pragma unroll
        for (int gi = 0; gi < 4; ++gi)
            ofh[l][gi] = *reinterpret_cast<const uint4*>(
                tbl + (l << 11) + (((wv << 2) + gi) << 5) + (quad << 3));
    uint4 ofo[2];
    if (wv < 4) {
        ofo[0] = *reinterpret_cast<const uint4*>(tbl + 6144 + (wv << 6) + (quad << 3));
        ofo[1] = *reinterpret_cast<const uint4*>(tbl + 6144 + (wv << 6) + 32 + (quad << 3));
    }

    const char* accb = (const char*)smem + nn * ROW_BYTES;   // act row = nn
    char* accw = (char*)smem;

    // prefetch regs for the x tile (waves 8..15: 512 thr x 16 floats)
    const int pr = (t - 512) >> 5;        // row 0..15 (valid for wv>=8)
    const int pc = (t & 31) << 4;         // float col 0..496
    uint_t px[8];
    if (wv >= 8) {
        const float4* src = reinterpret_cast<const float4*>(
            x + ((size_t)blockIdx.x * 16 + pr) * 512 + pc);
        float4 a0 = src[0], a1 = src[1], a2 = src[2], a3 = src[3];
        px[0] = pack2bf(a0.x, a0.y); px[1] = pack2bf(a0.z, a0.w);
        px[2] = pack2bf(a1.x, a1.y); px[3] = pack2bf(a1.z, a1.w);
        px[4] = pack2bf(a2.x, a2.y); px[5] = pack2bf(a2.z, a2.w);
        px[6] = pack2bf(a3.x, a3.y); px[7] = pack2bf(a3.z, a3.w);
    }

    #pragma unroll 1
    for (int it = 0; it < NTILES; ++it) {
        const int row0 = (it * 256 + blockIdx.x) * 16;

        // ---- layer-1 activation gathers: straight from global x (VM pipe),
        // issued before the barriers so latency overlaps the x-dump ----
        const float* xrow = x + (size_t)(row0 + nn) * 512;
        float f0[4][8];
        #pragma unroll
        for (int gi = 0; gi < 4; ++gi) {
            const uint4 o = ofh[0][gi];
            f0[gi][0] = xrow[o.x & 0xFFFFu]; f0[gi][1] = xrow[o.x >> 16];
            f0[gi][2] = xrow[o.y & 0xFFFFu]; f0[gi][3] = xrow[o.y >> 16];
            f0[gi][4] = xrow[o.z & 0xFFFFu]; f0[gi][5] = xrow[o.z >> 16];
            f0[gi][6] = xrow[o.w & 0xFFFFu]; f0[gi][7] = xrow[o.w >> 16];
        }

        __syncthreads();   // prev tile's head gathers done -> x region free
        if (wv >= 8) {     // dump prefetched x: 16 u16 = 32 B as 4x b64
            uint2* d = reinterpret_cast<uint2*>(accw + pr * ROW_BYTES + pc * 2);
            d[0] = make_uint2(px[0], px[1]);
            d[1] = make_uint2(px[2], px[3]);
            d[2] = make_uint2(px[4], px[5]);
            d[3] = make_uint2(px[6], px[7]);
        }
        __syncthreads();

        // ---- layer 1 (acts from registers; quad3 = bias/zero pad consts) ----
        {
            const int g0 = wv << 2;
            #pragma unroll
            for (int gi = 0; gi < 4; ++gi) {
                short8 af;
                af[0] = q3 ? (short)0x3f80 : (short)f2bf(f0[gi][0]);
                #pragma unroll
                for (int j = 1; j < 8; ++j)
                    af[j] = q3 ? (short)0 : (short)f2bf(f0[gi][j]);
                const short8 bfr = *reinterpret_cast<const short8*>(
                    ws + ((size_t)(g0 + gi) * 64 + lane) * 8);
                f32x4 z = { 0.f, 0.f, 0.f, 0.f };
                f32x4 acc = __builtin_amdgcn_mfma_f32_16x16x32_bf16(bfr, af, z, 0, 0, 0);
                uint2 q;
                q.x = pack2bf(fast_tanh(acc[0]), fast_tanh(acc[1]));
                q.y = pack2bf(fast_tanh(acc[2]), fast_tanh(acc[3]));
                *reinterpret_cast<uint2*>(
                    (char*)smem + nn * ROW_BYTES +
                    (512 + (g0 + gi) * 16 + quad * 4) * 2) = q;
            }
            __syncthreads();
        }

        // ---- layers 2,3 (LDS gathers, offsets from persistent regs) ----
        #pragma unroll
        for (int l = 1; l < 3; ++l) {
            const int out_base = 512 + l * 1024;
            const int g0 = wv << 2;
            short8 af[4];
            #pragma unroll
            for (int gi = 0; gi < 4; ++gi) {
                const uint4 o = ofh[l][gi];
                af[gi][0] = *(const short*)(accb + (o.x & 0xFFFFu));
                af[gi][1] = *(const short*)(accb + (o.x >> 16));
                af[gi][2] = *(const short*)(accb + (o.y & 0xFFFFu));
                af[gi][3] = *(const short*)(accb + (o.y >> 16));
                af[gi][4] = *(const short*)(accb + (o.z & 0xFFFFu));
                af[gi][5] = *(const short*)(accb + (o.z >> 16));
                af[gi][6] = *(const short*)(accb + (o.w & 0xFFFFu));
                af[gi][7] = *(const short*)(accb + (o.w >> 16));
            }
            #pragma unroll
            for (int gi = 0; gi < 4; ++gi) {
                const short8 bfr = *reinterpret_cast<const short8*>(
                    ws + (((size_t)l * 64 + g0 + gi) * 64 + lane) * 8);
                f32x4 z = { 0.f, 0.f, 0.f, 0.f };
                f32x4 acc = __builtin_amdgcn_mfma_f32_16x16x32_bf16(bfr, af[gi], z, 0, 0, 0);
                uint2 q;
                q.x = pack2bf(fast_tanh(acc[0]), fast_tanh(acc[1]));
                q.y = pack2bf(fast_tanh(acc[2]), fast_tanh(acc[3]));
                *reinterpret_cast<uint2*>(
                    (char*)smem + nn * ROW_BYTES +
                    (out_base + (g0 + gi) * 16 + quad * 4) * 2) = q;
            }
            __syncthreads();
        }

        // ---- head (waves 0..3) and next-x prefetch (waves 8..15) ----
        if (wv < 4) {
            const int go = wv;
            short8 af[2];
            #pragma unroll
            for (int s = 0; s < 2; ++s) {
                const uint4 o = ofo[s];
                af[s][0] = *(const short*)(accb + (o.x & 0xFFFFu));
                af[s][1] = *(const short*)(accb + (o.x >> 16));
                af[s][2] = *(const short*)(accb + (o.y & 0xFFFFu));
                af[s][3] = *(const short*)(accb + (o.y >> 16));
                af[s][4] = *(const short*)(accb + (o.z & 0xFFFFu));
                af[s][5] = *(const short*)(accb + (o.z >> 16));
                af[s][6] = *(const short*)(accb + (o.w & 0xFFFFu));
                af[s][7] = *(const short*)(accb + (o.w >> 16));
            }
            const short8 bf0 = *reinterpret_cast<const short8*>(
                ws + (12288 + ((size_t)go * 2 + 0) * 64 + lane) * 8);
            const short8 bf1 = *reinterpret_cast<const short8*>(
                ws + (12288 + ((size_t)go * 2 + 1) * 64 + lane) * 8);
            f32x4 z = { 0.f, 0.f, 0.f, 0.f };
            f32x4 a0 = __builtin_amdgcn_mfma_f32_16x16x32_bf16(bf0, af[0], z, 0, 0, 0);
            f32x4 a1 = __builtin_amdgcn_mfma_f32_16x16x32_bf16(bf1, af[1], z, 0, 0, 0);
            float4 v = make_float4(a0[0] + a1[0], a0[1] + a1[1],
                                   a0[2] + a1[2], a0[3] + a1[3]);
            *reinterpret_cast<float4*>(
                out + (size_t)(row0 + nn) * 64 + go * 16 + quad * 4) = v;
        }
        if (wv >= 8 && it + 1 < NTILES) {
            const float4* src = reinterpret_cast<const float4*>(
                x + (((size_t)(it + 1) * 256 + blockIdx.x) * 16 + pr) * 512 + pc);
            float4 a0 = src[0], a1 = src[1], a2 = src[2], a3 = src[3];
            px[0] = pack2bf(a0.x, a0.y); px[1] = pack2bf(a0.z, a0.w);
            px[2] = pack2bf(a1.x, a1.y); px[3] = pack2bf(a1.z, a1.w);
            px[4] = pack2bf(a2.x, a2.y); px[5] = pack2bf(a2.z, a2.w);
            px[6] = pack2bf(a3.x, a3.y); px[7] = pack2bf(a3.z, a3.w);
        }
    }
}

extern "C" void kernel_launch(void* const* d_in, const int* in_sizes, int n_in,
                              void* d_out, int out_size, void* d_ws, size_t ws_size,
                              hipStream_t stream) {
    const float* x  = (const float*)d_in[0];
    const float* W1 = (const float*)d_in[1];
    const float* b1 = (const float*)d_in[2];
    const float* W2 = (const float*)d_in[3];
    const float* b2 = (const float*)d_in[4];
    const float* W3 = (const float*)d_in[5];
    const float* b3 = (const float*)d_in[6];
    const float* Wo = (const float*)d_in[7];
    const float* bo = (const float*)d_in[8];
    const int* idx1 = (const int*)d_in[9];
    const int* idx2 = (const int*)d_in[10];
    const int* idx3 = (const int*)d_in[11];
    const int* idxo = (const int*)d_in[12];
    float* out = (float*)d_out;

    (void)hipFuncSetAttribute((const void*)demodel_mfma,
                              hipFuncAttributeMaxDynamicSharedMemorySize,
                              LDS_BYTES);

    convert_weights<<<75, 256, 0, stream>>>(W1, b1, W2, b2, W3, b3, Wo, bo,
                                            idx1, idx2, idx3, idxo,
                                            (ushort_t*)d_ws);

    demodel_mfma<<<256, 1024, LDS_BYTES, stream>>>(
        x, (const ushort_t*)d_ws, out);
}

// Round 10
// 148.801 us; speedup vs baseline: 1.5895x; 1.5895x over previous
//
#include <hip/hip_runtime.h>
#include <hip/hip_bf16.h>

// DirectEncodingModel via MFMA (transposed: D^T = mfma(W-frag, act-frag)).
// Block = 1024 thr (16 waves) owns a 16-row acc tile in LDS; wave w does 4
// groups/layer; persistent grid=256, 4 tiles/block.
// R10 = R8 structure + gather offsets hoisted ONCE into persistent VGPRs as
// packed u16 (one uint4 per group per lane; 48+8 VGPRs), removing all
// per-tile LDS offset reads (~25% of the LDS-pipe budget that bounds R8).
// R9's global-x gathers + big arrays are REVERTED (222 MB fetch + spills).
// Bias rides in K-pad slot k=24/k=48 against a 1.0 pad column; C starts 0.
// Layouts (HW-verified): A[m=lane&15][k=(lane>>4)*8+j];
//   B[k=(lane>>4)*8+j][n=lane&15]; C/D col=lane&15, row=(lane>>4)*4+reg.

typedef unsigned short ushort_t;
typedef unsigned int uint_t;
typedef __attribute__((ext_vector_type(8))) short short8;   // 8 bf16 frag
typedef __attribute__((ext_vector_type(4))) float f32x4;    // MFMA acc

#define ACC_STRIDE 3588                   // u16 per row; 1794 dw == 2 mod 32
#define ROW_BYTES (ACC_STRIDE * 2)        // 7176
#define PAD_ONE 3584                      // pad col holding bf16 1.0
#define ONE_BYTE (PAD_ONE * 2)            // 7168 (fits u16)
#define ZERO_BYTE (3586 * 2)              // 7172 (col 3586 == 0)
#define ACC_U16 (16 * ACC_STRIDE)         // 57408 u16 = 114816 B
#define TBL_BYTES 12800                   // compact u16 offset table
#define LDS_BYTES (ACC_U16 * 2 + TBL_BYTES)    // 127616 B

// d_ws layout (bytes): frags hidden [0,196608) + head [196608,204800),
// compact u16 offset table at [204800, 217600).
#define OFF_B 204800

__device__ __forceinline__ ushort_t f2bf(float f) {
    __hip_bfloat16 h = __float2bfloat16(f);
    union { __hip_bfloat16 h; ushort_t u; } v;
    v.h = h;
    return v.u;
}

__device__ __forceinline__ uint_t pack2bf(float lo, float hi) {
    return (uint_t)f2bf(lo) | ((uint_t)f2bf(hi) << 16);
}

// tanh(x) = 1 - 2/(e^2x + 1); exp saturation gives exact +-1 tails, no clamp.
__device__ __forceinline__ float fast_tanh(float x) {
    float e = __expf(2.0f * x);
    return fmaf(-2.0f, __builtin_amdgcn_rcpf(e + 1.0f), 1.0f);
}

// ---- Pre-pack weights (B-frag order, bias in k=24/k=48 slot) + compact
// u16 LDS byte-offset table (K-pad -> ONE/ZERO pad cols). ----
__global__ __launch_bounds__(256)
void convert_weights(const float* __restrict__ W1, const float* __restrict__ b1,
                     const float* __restrict__ W2, const float* __restrict__ b2,
                     const float* __restrict__ W3, const float* __restrict__ b3,
                     const float* __restrict__ Wo, const float* __restrict__ bo,
                     const int* __restrict__ idx1, const int* __restrict__ idx2,
                     const int* __restrict__ idx3, const int* __restrict__ idxo,
                     ushort_t* __restrict__ ws)
{
    const int tid = blockIdx.x * 256 + threadIdx.x;
    const int lane = tid & 63;
    const int nn = lane & 15;
    const int quad = lane >> 4;
    if (tid < 12288) {
        const int g = (tid >> 6) & 63;
        const int l = tid >> 12;   // 0..2
        const float* W = (l == 0) ? W1 : (l == 1) ? W2 : W3;
        const float* bb = (l == 0) ? b1 : (l == 1) ? b2 : b3;
        const float* Wg = W + g * 384;
        ushort_t v[8];
        #pragma unroll
        for (int j = 0; j < 8; ++j) {
            const int k = quad * 8 + j;
            v[j] = (k < 24) ? f2bf(Wg[k * 16 + nn])
                 : (k == 24) ? f2bf(bb[g * 16 + nn]) : (ushort_t)0;
        }
        ushort4* dst = reinterpret_cast<ushort4*>(ws + (size_t)tid * 8);
        dst[0] = make_ushort4(v[0], v[1], v[2], v[3]);
        dst[1] = make_ushort4(v[4], v[5], v[6], v[7]);
    } else if (tid < 12800) {
        const int h = tid - 12288;
        const int gs = h >> 6;          // 0..7: go*2+step
        const int go = gs >> 1;
        const int step = gs & 1;
        const float* Wg = Wo + go * 768;
        ushort_t v[8];
        #pragma unroll
        for (int j = 0; j < 8; ++j) {
            const int k = step * 32 + quad * 8 + j;
            v[j] = (k < 48) ? f2bf(Wg[k * 16 + nn])
                 : (k == 48) ? f2bf(bo[go * 16 + nn]) : (ushort_t)0;
        }
        ushort4* dst = reinterpret_cast<ushort4*>(ws + (size_t)tid * 8);
        dst[0] = make_ushort4(v[0], v[1], v[2], v[3]);
        dst[1] = make_ushort4(v[4], v[5], v[6], v[7]);
    } else if (tid < 18944) {
        // hidden compact offsets (u16 LDS byte offsets): e = l*2048+g*32+k
        const int e = tid - 12800;
        const int l = e >> 11;
        const int g = (e >> 5) & 63;
        const int k = e & 31;
        const int* idx = (l == 0) ? idx1 : (l == 1) ? idx2 : idx3;
        const ushort_t v = (k < 24) ? (ushort_t)(idx[g * 24 + k] * 2)
                         : (k == 24) ? (ushort_t)ONE_BYTE : (ushort_t)ZERO_BYTE;
        reinterpret_cast<ushort_t*>((char*)ws + OFF_B)[e] = v;
    } else if (tid < 19200) {
        // head compact offsets: e = go*64 + k, appended after 6144
        const int e = tid - 18944;
        const int go = e >> 6;
        const int k = e & 63;
        const ushort_t v = (k < 48) ? (ushort_t)(idxo[go * 48 + k] * 2)
                         : (k == 48) ? (ushort_t)ONE_BYTE : (ushort_t)ZERO_BYTE;
        reinterpret_cast<ushort_t*>((char*)ws + OFF_B)[6144 + e] = v;
    }
}

#define NTILES 4   // 16384 rows / 16 per tile / 256 blocks

__global__ __launch_bounds__(1024)
void demodel_mfma(const float* __restrict__ x,
                  const ushort_t* __restrict__ ws,
                  float* __restrict__ out)
{
    extern __shared__ __align__(16) ushort_t smem[];
    const int t = threadIdx.x;
    const int lane = t & 63;
    const int wv = t >> 6;               // wave 0..15
    const int nn = lane & 15;
    const int quad = lane >> 4;

    // ---- stage compact offset table (12800 B) + pad cols ----
    if (t < TBL_BYTES / 16)
        reinterpret_cast<uint4*>(smem + ACC_U16)[t] =
            reinterpret_cast<const uint4*>((const char*)ws + OFF_B)[t];
    if (t < 16) {   // pad cols per row: [3584]=1.0, [3585..3587]=0
        uint2* p = reinterpret_cast<uint2*>((char*)smem + t * ROW_BYTES + ONE_BYTE);
        *p = make_uint2(0x00003f80u, 0u);
    }
    __syncthreads();

    // ---- hoist all gather offsets (packed u16) into persistent VGPRs ----
    const ushort_t* tbl = smem + ACC_U16;
    uint4 ofh[3][4];
    #pragma unroll
    for (int l = 0; l < 3; ++l)
        #pragma unroll
        for (int gi = 0; gi < 4; ++gi)
            ofh[l][gi] = *reinterpret_cast<const uint4*>(
                tbl + (l << 11) + (((wv << 2) + gi) << 5) + (quad << 3));
    uint4 ofo0, ofo1;
    if (wv < 4) {
        ofo0 = *reinterpret_cast<const uint4*>(tbl + 6144 + (wv << 6) + (quad << 3));
        ofo1 = *reinterpret_cast<const uint4*>(tbl + 6144 + (wv << 6) + 32 + (quad << 3));
    }

    const char* accb = (const char*)smem + nn * ROW_BYTES;   // act row = nn
    char* accw = (char*)smem;

    // prefetch regs for the x tile (waves 8..15: 512 thr x 16 floats)
    const int pr = (t - 512) >> 5;        // row 0..15 (valid for wv>=8)
    const int pc = (t & 31) << 4;         // float col 0..496
    uint_t px[8];
    if (wv >= 8) {
        const float4* src = reinterpret_cast<const float4*>(
            x + ((size_t)blockIdx.x * 16 + pr) * 512 + pc);
        float4 a0 = src[0], a1 = src[1], a2 = src[2], a3 = src[3];
        px[0] = pack2bf(a0.x, a0.y); px[1] = pack2bf(a0.z, a0.w);
        px[2] = pack2bf(a1.x, a1.y); px[3] = pack2bf(a1.z, a1.w);
        px[4] = pack2bf(a2.x, a2.y); px[5] = pack2bf(a2.z, a2.w);
        px[6] = pack2bf(a3.x, a3.y); px[7] = pack2bf(a3.z, a3.w);
    }

    #pragma unroll 1
    for (int it = 0; it < NTILES; ++it) {
        const int row0 = (it * 256 + blockIdx.x) * 16;

        __syncthreads();   // prev tile's head gathers done -> x region free
        if (wv >= 8) {     // dump prefetched x: 16 u16 = 32 B as 4x b64
            uint2* d = reinterpret_cast<uint2*>(accw + pr * ROW_BYTES + pc * 2);
            d[0] = make_uint2(px[0], px[1]);
            d[1] = make_uint2(px[2], px[3]);
            d[2] = make_uint2(px[4], px[5]);
            d[3] = make_uint2(px[6], px[7]);
        }
        __syncthreads();

        // ---- 3 hidden layers; per-group serial (TLP from 16 waves) ----
        #pragma unroll 1
        for (int l = 0; l < 3; ++l) {
            const int out_base = 512 + l * 1024;
            const int g0 = wv << 2;
            #pragma unroll
            for (int gi = 0; gi < 4; ++gi) {
                const uint4 o = ofh[l][gi];
                short8 af;
                af[0] = *(const short*)(accb + (o.x & 0xFFFFu));
                af[1] = *(const short*)(accb + (o.x >> 16));
                af[2] = *(const short*)(accb + (o.y & 0xFFFFu));
                af[3] = *(const short*)(accb + (o.y >> 16));
                af[4] = *(const short*)(accb + (o.z & 0xFFFFu));
                af[5] = *(const short*)(accb + (o.z >> 16));
                af[6] = *(const short*)(accb + (o.w & 0xFFFFu));
                af[7] = *(const short*)(accb + (o.w >> 16));
                const short8 bfr = *reinterpret_cast<const short8*>(
                    ws + (((size_t)l * 64 + g0 + gi) * 64 + lane) * 8);
                f32x4 z = { 0.f, 0.f, 0.f, 0.f };
                f32x4 acc = __builtin_amdgcn_mfma_f32_16x16x32_bf16(bfr, af, z, 0, 0, 0);
                uint2 q;
                q.x = pack2bf(fast_tanh(acc[0]), fast_tanh(acc[1]));
                q.y = pack2bf(fast_tanh(acc[2]), fast_tanh(acc[3]));
                *reinterpret_cast<uint2*>(
                    (char*)smem + nn * ROW_BYTES +
                    (out_base + (g0 + gi) * 16 + quad * 4) * 2) = q;
            }
            __syncthreads();
        }

        // ---- head (waves 0..3) and next-x prefetch (waves 8..15) ----
        if (wv < 4) {
            const int go = wv;
            f32x4 acc_sum;
            {
                const uint4 o = ofo0;
                short8 af;
                af[0] = *(const short*)(accb + (o.x & 0xFFFFu));
                af[1] = *(const short*)(accb + (o.x >> 16));
                af[2] = *(const short*)(accb + (o.y & 0xFFFFu));
                af[3] = *(const short*)(accb + (o.y >> 16));
                af[4] = *(const short*)(accb + (o.z & 0xFFFFu));
                af[5] = *(const short*)(accb + (o.z >> 16));
                af[6] = *(const short*)(accb + (o.w & 0xFFFFu));
                af[7] = *(const short*)(accb + (o.w >> 16));
                const short8 bfr = *reinterpret_cast<const short8*>(
                    ws + (12288 + ((size_t)go * 2 + 0) * 64 + lane) * 8);
                f32x4 z = { 0.f, 0.f, 0.f, 0.f };
                acc_sum = __builtin_amdgcn_mfma_f32_16x16x32_bf16(bfr, af, z, 0, 0, 0);
            }
            {
                const uint4 o = ofo1;
                short8 af;
                af[0] = *(const short*)(accb + (o.x & 0xFFFFu));
                af[1] = *(const short*)(accb + (o.x >> 16));
                af[2] = *(const short*)(accb + (o.y & 0xFFFFu));
                af[3] = *(const short*)(accb + (o.y >> 16));
                af[4] = *(const short*)(accb + (o.z & 0xFFFFu));
                af[5] = *(const short*)(accb + (o.z >> 16));
                af[6] = *(const short*)(accb + (o.w & 0xFFFFu));
                af[7] = *(const short*)(accb + (o.w >> 16));
                const short8 bfr = *reinterpret_cast<const short8*>(
                    ws + (12288 + ((size_t)go * 2 + 1) * 64 + lane) * 8);
                acc_sum = __builtin_amdgcn_mfma_f32_16x16x32_bf16(bfr, af, acc_sum, 0, 0, 0);
            }
            // lane nn: row=row0+nn, cols go*16+quad*4+{0..3} -> one dwordx4
            float4 v = make_float4(acc_sum[0], acc_sum[1], acc_sum[2], acc_sum[3]);
            *reinterpret_cast<float4*>(
                out + (size_t)(row0 + nn) * 64 + go * 16 + quad * 4) = v;
        }
        if (wv >= 8 && it + 1 < NTILES) {
            const float4* src = reinterpret_cast<const float4*>(
                x + (((size_t)(it + 1) * 256 + blockIdx.x) * 16 + pr) * 512 + pc);
            float4 a0 = src[0], a1 = src[1], a2 = src[2], a3 = src[3];
            px[0] = pack2bf(a0.x, a0.y); px[1] = pack2bf(a0.z, a0.w);
            px[2] = pack2bf(a1.x, a1.y); px[3] = pack2bf(a1.z, a1.w);
            px[4] = pack2bf(a2.x, a2.y); px[5] = pack2bf(a2.z, a2.w);
            px[6] = pack2bf(a3.x, a3.y); px[7] = pack2bf(a3.z, a3.w);
        }
    }
}

extern "C" void kernel_launch(void* const* d_in, const int* in_sizes, int n_in,
                              void* d_out, int out_size, void* d_ws, size_t ws_size,
                              hipStream_t stream) {
    const float* x  = (const float*)d_in[0];
    const float* W1 = (const float*)d_in[1];
    const float* b1 = (const float*)d_in[2];
    const float* W2 = (const float*)d_in[3];
    const float* b2 = (const float*)d_in[4];
    const float* W3 = (const float*)d_in[5];
    const float* b3 = (const float*)d_in[6];
    const float* Wo = (const float*)d_in[7];
    const float* bo = (const float*)d_in[8];
    const int* idx1 = (const int*)d_in[9];
    const int* idx2 = (const int*)d_in[10];
    const int* idx3 = (const int*)d_in[11];
    const int* idxo = (const int*)d_in[12];
    float* out = (float*)d_out;

    (void)hipFuncSetAttribute((const void*)demodel_mfma,
                              hipFuncAttributeMaxDynamicSharedMemorySize,
                              LDS_BYTES);

    convert_weights<<<75, 256, 0, stream>>>(W1, b1, W2, b2, W3, b3, Wo, bo,
                                            idx1, idx2, idx3, idxo,
                                            (ushort_t*)d_ws);

    demodel_mfma<<<256, 1024, LDS_BYTES, stream>>>(
        x, (const ushort_t*)d_ws, out);
}